// Round 9
// baseline (2595.033 us; speedup 1.0000x reference)
//
#include <hip/hip_runtime.h>

// RoutingCapsules on MI355X (gfx950)
// x: [B=32, Nin=2048, Din=16] f32
// W: [1, Nin=2048, Nout=64, Dout=32, Din=16] f32
// out v: [B=32, Nout=64, Dout=32] f32
//
// 3 fused W-sweeps (u_hat recomputed, never materialized):
//   pass1: c uniform     -> s1 = (1/64) sum_n u_hat        -> v1  (round-8 kernel, proven ~75us)
//   pass2: logits=u.v1   -> s2                             -> v2  (NEW wave-softmax kernel)
//   pass3: logits=u.(v1+v2)                                -> v3 = out
//
// Round-9: round 8 still paid ~160us/pass of softmax machinery (32 shfl + 16
// ustash LDS ops + 2 barriers + half-idle phase B per thread per nn).
// New pass2/3 mapping: TPB=512, wave = batch bb, lane = o, ALL 32 d in regs.
// Softmax over o is then fully in-wave (1 exp + 6 shfl + 1 div), no barriers,
// no ustash. u[32] lives only within one n-iteration (cap-128 fits: forced
// live ~92). W reads: per-lane 2KB contiguous; 8 waves read the same lines,
// per-n lockstep barrier lets L1 filter 7/8.

#define B_   32
#define NIN  2048
#define DIN  16
#define NOUT 64
#define DOUT 32
#define BQ   8                          // batches per block
#define NCHB 16                         // n per block
#define CG   (NIN / NCHB)               // 128 chunk-groups
#define NBLK (CG * (B_ / BQ))           // 512 blocks
#define TPB  1024                       // pass1 / fallback kernel
#define TPB2 512                        // pass2/3 wave-softmax kernel
#define PART_PER_BLK (BQ * NOUT * DOUT / 2)   // 8192 float2 per block (64 KB)

// ---------------- round-8 kernel (pass1 + atomic fallback) ----------------
template<int PASS, bool ATOMIC>
__global__ __launch_bounds__(TPB)
void caps_pass(const float* __restrict__ W, const float* __restrict__ x,
               const float* __restrict__ v_in, float* __restrict__ s_out,
               float2* __restrict__ part)
{
    const int t    = threadIdx.x;
    const int o    = t >> 4;
    const int dg   = t & 15;
    const int d0   = dg << 1;
    const int lane = t & 63;
    const int wid  = t >> 6;

    const int bid  = blockIdx.x;
    const int xcd  = bid & 7;
    const int j    = bid >> 3;
    const int cg   = xcd * (CG / 8) + (j >> 2);
    const int quad = j & 3;
    const int nbase = cg * NCHB;
    const int bbase = quad * BQ;

    __shared__ float4 xs[BQ][NCHB * DIN / 4];

    if (t < BQ * NCHB * DIN / 4) {
        const int bb = t >> 6;
        const int k  = t & 63;
        xs[bb][k] = ((const float4*)x)[(size_t)(bbase + bb) * (NIN * DIN / 4)
                                       + (size_t)nbase * (DIN / 4) + k];
    }

    float acc0[BQ], acc1[BQ];
#pragma unroll
    for (int bb = 0; bb < BQ; ++bb) { acc0[bb] = 0.f; acc1[bb] = 0.f; }

    __syncthreads();

    if constexpr (PASS == 1) {
        for (int nn = 0; nn < NCHB; ++nn) {
            const float4* wp = (const float4*)(W +
                (((size_t)(nbase + nn) * NOUT + o) * DOUT + d0) * DIN);
            float4 w[8];
#pragma unroll
            for (int q = 0; q < 8; ++q) w[q] = wp[q];
#pragma unroll
            for (int bb = 0; bb < BQ; ++bb) {
                const float4* xr = &xs[bb][nn * 4];
                float u0 = 0.f, u1 = 0.f;
#pragma unroll
                for (int q = 0; q < 4; ++q) {
                    const float4 xv = xr[q];
                    u0 += w[q].x*xv.x + w[q].y*xv.y + w[q].z*xv.z + w[q].w*xv.w;
                    u1 += w[4+q].x*xv.x + w[4+q].y*xv.y + w[4+q].z*xv.z + w[4+q].w*xv.w;
                }
                acc0[bb] += u0;
                acc1[bb] += u1;
            }
        }
    } else {
        __shared__ float  lg[BQ * NOUT];
        __shared__ float  cs[BQ * NOUT];
        __shared__ float2 ustash[BQ][TPB];
        for (int nn = 0; nn < NCHB; ++nn) {
            const float4* wp = (const float4*)(W +
                (((size_t)(nbase + nn) * NOUT + o) * DOUT + d0) * DIN);
            float4 w[8];
#pragma unroll
            for (int q = 0; q < 8; ++q) w[q] = wp[q];
#pragma unroll
            for (int bb = 0; bb < BQ; ++bb) {
                const float4* xr = &xs[bb][nn * 4];
                float u0 = 0.f, u1 = 0.f;
#pragma unroll
                for (int q = 0; q < 4; ++q) {
                    const float4 xv = xr[q];
                    u0 += w[q].x*xv.x + w[q].y*xv.y + w[q].z*xv.z + w[q].w*xv.w;
                    u1 += w[4+q].x*xv.x + w[4+q].y*xv.y + w[4+q].z*xv.z + w[4+q].w*xv.w;
                }
                const float2 vv = ((const float2*)v_in)[
                    (size_t)(bbase + bb) * (NOUT * DOUT / 2) + o * (DOUT / 2) + dg];
                float p = u0 * vv.x + u1 * vv.y;
                p += __shfl_xor(p, 1);
                p += __shfl_xor(p, 2);
                p += __shfl_xor(p, 4);
                p += __shfl_xor(p, 8);
                if (dg == 0) lg[bb * NOUT + o] = p;
                ustash[bb][t] = make_float2(u0, u1);
            }
            __syncthreads();
            if (wid < BQ) {
                const float e = __expf(lg[wid * NOUT + lane]);
                float sm = e;
#pragma unroll
                for (int m = 1; m < 64; m <<= 1) sm += __shfl_xor(sm, m);
                cs[wid * NOUT + lane] = e / sm;
            }
            __syncthreads();
#pragma unroll
            for (int bb = 0; bb < BQ; ++bb) {
                const float c = cs[bb * NOUT + o];
                const float2 u = ustash[bb][t];
                acc0[bb] += c * u.x;
                acc1[bb] += c * u.y;
            }
        }
    }

    const float scale = (PASS == 1) ? (1.0f / 64.0f) : 1.0f;
    if constexpr (ATOMIC) {
#pragma unroll
        for (int bb = 0; bb < BQ; ++bb) {
            float* dst = &s_out[((size_t)(bbase + bb) * NOUT + o) * DOUT + d0];
            atomicAdd(dst,     acc0[bb] * scale);
            atomicAdd(dst + 1, acc1[bb] * scale);
        }
    } else {
        float2* base = part + (size_t)(cg * 4 + quad) * PART_PER_BLK;
#pragma unroll
        for (int bb = 0; bb < BQ; ++bb)
            base[bb * (NOUT * DOUT / 2) + o * (DOUT / 2) + dg] =
                make_float2(acc0[bb] * scale, acc1[bb] * scale);
    }
}

// ---------------- NEW pass2/3 kernel: wave-softmax, lane = o ----------------
__global__ __launch_bounds__(TPB2)
void caps_pass23(const float* __restrict__ W, const float* __restrict__ x,
                 const float* __restrict__ v_in, float2* __restrict__ part)
{
    const int t    = threadIdx.x;          // 0..511
    const int lane = t & 63;               // = o (capsule-out)
    const int wid  = t >> 6;               // = bb (0..7)

    const int bid  = blockIdx.x;
    const int xcd  = bid & 7;
    const int j    = bid >> 3;
    const int cg   = xcd * (CG / 8) + (j >> 2);
    const int quad = j & 3;
    const int nbase = cg * NCHB;
    const int bbase = quad * BQ;

    __shared__ float4 xs[BQ][NCHB][DIN / 4];      // 8 KB
    __shared__ float  vs[BQ][NOUT][DOUT + 1];     // 67.5 KB, +1 pad kills bank conflicts

    // stage x slice: 512 float4
    {
        const int bb = t >> 6, r = t & 63, nn = r >> 2, q = r & 3;
        xs[bb][nn][q] = ((const float4*)x)[(size_t)(bbase + bb) * (NIN * DIN / 4)
                                           + (size_t)(nbase + nn) * (DIN / 4) + q];
    }
    // stage v into padded LDS: thread (bb=wid, o=lane) copies its 32-float row
    {
        const float* vp = v_in + ((size_t)(bbase + wid) * NOUT + lane) * DOUT;
        for (int d = 0; d < DOUT; ++d) vs[wid][lane][d] = vp[d];
    }
    __syncthreads();

    float acc[DOUT];                               // 32 regs, persists over n
#pragma unroll
    for (int d = 0; d < DOUT; ++d) acc[d] = 0.f;

    for (int nn = 0; nn < NCHB; ++nn) {
        __syncthreads();   // lockstep: 8 waves read the SAME W[n] lines -> L1 filters
        const int n = nbase + nn;
        const float4 x0 = xs[wid][nn][0], x1 = xs[wid][nn][1],
                     x2 = xs[wid][nn][2], x3 = xs[wid][nn][3];
        const float4* wp = (const float4*)(W + ((size_t)n * NOUT + lane) * (DOUT * DIN));
        float u[DOUT];                             // 32 regs, dies at end of iter
        float logit = 0.f;
#pragma unroll
        for (int d = 0; d < DOUT; ++d) {           // full unroll: static u[] indexing
            const float4 wa = wp[d * 4 + 0], wb = wp[d * 4 + 1],
                         wc = wp[d * 4 + 2], wd = wp[d * 4 + 3];
            const float ud = wa.x*x0.x + wa.y*x0.y + wa.z*x0.z + wa.w*x0.w
                           + wb.x*x1.x + wb.y*x1.y + wb.z*x1.z + wb.w*x1.w
                           + wc.x*x2.x + wc.y*x2.y + wc.z*x2.z + wc.w*x2.w
                           + wd.x*x3.x + wd.y*x3.y + wd.z*x3.z + wd.w*x3.w;
            u[d] = ud;
            logit += ud * vs[wid][lane][d];
        }
        // in-wave softmax over o = 64 lanes (no max-sub: |logit| << 88)
        const float e = __expf(logit);
        float sm = e;
#pragma unroll
        for (int m = 1; m < 64; m <<= 1) sm += __shfl_xor(sm, m);
        const float c = e / sm;
#pragma unroll
        for (int d = 0; d < DOUT; ++d) acc[d] += c * u[d];
    }

    // partial store, float-layout identical to round-8: [bb][o][d]
    float* pb = (float*)(part + (size_t)(cg * 4 + quad) * PART_PER_BLK)
              + (size_t)wid * (NOUT * DOUT) + lane * DOUT;
#pragma unroll
    for (int d = 0; d < DOUT; d += 4)
        *(float4*)(pb + d) = make_float4(acc[d], acc[d+1], acc[d+2], acc[d+3]);
}

// sum 128 chunk-partials per element, then squash per (b,o) row (16 lanes)
__global__ __launch_bounds__(256)
void reduce_squash(const float2* __restrict__ part, float* __restrict__ vout,
                   int accumulate)
{
    const int id = blockIdx.x * 256 + threadIdx.x;   // 0..32767
    const int dg = id & 15;
    const int o  = (id >> 4) & 63;
    const int b  = id >> 10;
    const int quad = b >> 3, bb = b & 7;
    const size_t base = (size_t)bb * (NOUT * DOUT / 2) + o * (DOUT / 2) + dg;

    float2 a0 = make_float2(0.f, 0.f), a1 = make_float2(0.f, 0.f);
    for (int cg = 0; cg < CG; cg += 2) {
        const float2 p0 = part[(size_t)(cg * 4 + quad) * PART_PER_BLK + base];
        const float2 p1 = part[(size_t)((cg + 1) * 4 + quad) * PART_PER_BLK + base];
        a0.x += p0.x; a0.y += p0.y;
        a1.x += p1.x; a1.y += p1.y;
    }
    const float sx = a0.x + a1.x, sy = a0.y + a1.y;

    float sq = sx * sx + sy * sy;
    sq += __shfl_xor(sq, 1);
    sq += __shfl_xor(sq, 2);
    sq += __shfl_xor(sq, 4);
    sq += __shfl_xor(sq, 8);        // row (b,o) = 16-lane group
    const float f = sq / ((1.0f + sq) * sqrtf(sq + 1e-8f));

    float2* vo = (float2*)vout;
    float2 r = make_float2(sx * f, sy * f);
    if (accumulate) {
        const float2 old = vo[id];
        r.x += old.x; r.y += old.y;
    }
    vo[id] = r;
}

// fallback squash for the atomic path
__global__ void squash_k(const float* __restrict__ s, float* __restrict__ vout,
                         int accumulate)
{
    const int idx = blockIdx.x * 256 + threadIdx.x;
    const float val = s[idx];
    float sq = val * val;
#pragma unroll
    for (int m = 1; m < 32; m <<= 1) sq += __shfl_xor(sq, m);
    const float f = sq / ((1.0f + sq) * sqrtf(sq + 1e-8f));
    const float v = val * f;
    if (accumulate) vout[idx] += v;
    else            vout[idx] = v;
}

extern "C" void kernel_launch(void* const* d_in, const int* in_sizes, int n_in,
                              void* d_out, int out_size, void* d_ws, size_t ws_size,
                              hipStream_t stream)
{
    (void)in_sizes; (void)n_in; (void)out_size;
    const float* x = (const float*)d_in[0];
    const float* W = (const float*)d_in[1];
    float* out = (float*)d_out;

    const size_t partBytes = (size_t)NBLK * PART_PER_BLK * sizeof(float2); // 32 MB
    const size_t vBytes    = (size_t)B_ * NOUT * DOUT * sizeof(float);     // 256 KB

    if (ws_size >= partBytes + vBytes) {
        // ---- partial-sum path (no global atomics)
        float2* part = (float2*)d_ws;
        float*  vA   = (float*)((char*)d_ws + partBytes);

        caps_pass<1, false><<<dim3(NBLK), dim3(TPB), 0, stream>>>(W, x, nullptr, nullptr, part);
        reduce_squash<<<dim3(128), dim3(256), 0, stream>>>(part, vA, 0);   // vA = v1

        caps_pass23<<<dim3(NBLK), dim3(TPB2), 0, stream>>>(W, x, vA, part);
        reduce_squash<<<dim3(128), dim3(256), 0, stream>>>(part, vA, 1);   // vA = v1+v2

        caps_pass23<<<dim3(NBLK), dim3(TPB2), 0, stream>>>(W, x, vA, part);
        reduce_squash<<<dim3(128), dim3(256), 0, stream>>>(part, out, 0);  // out = v3
    } else {
        // ---- atomic fallback
        float* s  = (float*)d_ws;
        float* vA = s + B_ * NOUT * DOUT;

        hipMemsetAsync(s, 0, vBytes, stream);
        caps_pass<1, true><<<dim3(NBLK), dim3(TPB), 0, stream>>>(W, x, nullptr, s, nullptr);
        squash_k<<<dim3(256), dim3(256), 0, stream>>>(s, vA, 0);

        hipMemsetAsync(s, 0, vBytes, stream);
        caps_pass<2, true><<<dim3(NBLK), dim3(TPB), 0, stream>>>(W, x, vA, s, nullptr);
        squash_k<<<dim3(256), dim3(256), 0, stream>>>(s, vA, 1);

        hipMemsetAsync(s, 0, vBytes, stream);
        caps_pass<2, true><<<dim3(NBLK), dim3(TPB), 0, stream>>>(W, x, vA, s, nullptr);
        squash_k<<<dim3(256), dim3(256), 0, stream>>>(s, out, 0);
    }
}